// Round 8
// baseline (183.023 us; speedup 1.0000x reference)
//
#include <hip/hip_runtime.h>
#include <hip/hip_bf16.h>
#include <math.h>

#define B_ 2
#define NCLS_ 19
#define N_ 25600
#define C_ 256
#define MAXN_ 1024
#define THRESH_ 100
#define MAXSAMP_ 1024
#define NLIST_ (B_*NCLS_*2)
#define NHIST_ (B_*NCLS_)
#define NBLK_ 200              // (B_*N_+255)/256
#define CAP_ 6144
#define CAPL_ 25600            // fixed capacity per candidate list

typedef __attribute__((ext_vector_type(8))) short bf16x8;
typedef __attribute__((ext_vector_type(4))) float f32x4;

// ---------------- workspace layout (bytes) ----------------
constexpr size_t OFF_CURS = 0;                                   // NLIST ints + finish counter (512 B, memset each call)
constexpr size_t OFF_SELB = 512;
constexpr size_t OFF_SELP = OFF_SELB + (size_t)MAXN_*4;
constexpr size_t OFF_SELL = OFF_SELP + (size_t)MAXN_*4;
constexpr size_t OFF_SFH  = OFF_SELL + (size_t)MAXN_*4;          // MAXN*C bf16
constexpr size_t OFF_KMH  = OFF_SFH + (size_t)MAXN_*C_*2;        // 3*MAXN*C bf16
constexpr size_t OFF_PAF  = OFF_KMH + (size_t)3*MAXN_*C_*2;
constexpr size_t OFF_PAM  = OFF_PAF + (size_t)MAXN_*4;
constexpr size_t OFF_CAND = OFF_PAM + (size_t)MAXN_*4;           // NLIST*CAPL u64 (~15.6 MB)

__device__ __forceinline__ unsigned short f2bf(float x) {
    unsigned u = __float_as_uint(x);
    unsigned r = (u + 0x7FFFu + ((u >> 16) & 1u)) >> 16;   // RNE
    return (unsigned short)r;
}

// ---- mining plan recomputed from cursor counts (cheap: 76 L2-hot ints) ----
__device__ __forceinline__ void plan_takes(int ne, int nh, int n_view, int* h, int* e) {
    int nhk, nek;
    bool hb = 2*nh >= n_view, eb = 2*ne >= n_view;
    if (hb && eb)      { nhk = n_view/2; nek = n_view - nhk; }
    else if (hb)       { nek = ne;       nhk = n_view - nek; }
    else if (eb)       { nhk = nh;       nek = n_view - nhk; }
    else               { nhk = nh;       nek = ne; }
    *h = nhk < nh ? nhk : nh;
    *e = nek < ne ? nek : ne;
}

__device__ __forceinline__ int plan_total_n(const int* __restrict__ cursor, int* o_total) {
    int total = 0;
    for (int i = 0; i < NHIST_; ++i)
        if (cursor[2*i] + cursor[2*i+1] > THRESH_) total++;
    int n_view = 0;
    if (total > 0) { n_view = MAXSAMP_ / total; if (n_view > THRESH_) n_view = THRESH_; }
    int off = 0;
    for (int i = 0; i < NHIST_; ++i) {
        int ne = cursor[2*i], nh = cursor[2*i+1];
        if (ne + nh > THRESH_) { int h, e; plan_takes(ne, nh, n_view, &h, &e); off += h + e; }
    }
    if (o_total) *o_total = total;
    return off;
}

__device__ __forceinline__ void plan_slot(const int* __restrict__ cursor, int slot,
                                          int* h_take, int* e_take, int* off_out) {
    int total = 0;
    for (int i = 0; i < NHIST_; ++i)
        if (cursor[2*i] + cursor[2*i+1] > THRESH_) total++;
    int n_view = 0;
    if (total > 0) { n_view = MAXSAMP_ / total; if (n_view > THRESH_) n_view = THRESH_; }
    int off = 0, ht = 0, et = 0, myoff = 0;
    for (int i = 0; i < NHIST_; ++i) {
        int ne = cursor[2*i], nh = cursor[2*i+1];
        int h = 0, e = 0;
        if (ne + nh > THRESH_) plan_takes(ne, nh, n_view, &h, &e);
        if (i == slot) { ht = h; et = e; myoff = off; }
        off += h + e;
    }
    *h_take = ht; *e_take = et; *off_out = myoff;
}

// ---------------- 1. fused softmax/argmax + candidate scatter ----------------
__global__ void __launch_bounds__(256, 2)
k_softmax_scatter(const float* __restrict__ seg, const int* __restrict__ gt,
                  int* __restrict__ cursor, unsigned long long* __restrict__ cand) {
    __shared__ int lcnt[NLIST_];
    __shared__ int lbeg[NLIST_];
    int t = threadIdx.x;
    if (t < NLIST_) lcnt[t] = 0;
    __syncthreads();
    int idx = blockIdx.x * 256 + t;
    int L = -1, lp = 0;
    unsigned long long key = 0;
    if (idx < B_*N_) {
        int b = idx / N_, p = idx - b*N_;
        int lab = gt[idx];
        if (lab >= 0 && lab < NCLS_) {
            const float* base = seg + (size_t)b*NCLS_*N_ + p;
            float v[NCLS_];
            float mx = -INFINITY; int am = 0;
            #pragma unroll
            for (int k = 0; k < NCLS_; ++k) {
                float x = base[(size_t)k*N_];
                v[k] = x;
                if (x > mx) { mx = x; am = k; }
            }
            float ssum = 0.f, pv = 0.f;
            #pragma unroll
            for (int k = 0; k < NCLS_; ++k) {
                float e = expf(v[k] - mx);
                ssum += e;
                pv = (lab == k) ? e : pv;
            }
            pv /= ssum;
            int ishard = (am != lab) ? 1 : 0;
            L = (b*NCLS_ + lab)*2 + ishard;
            lp = atomicAdd(&lcnt[L], 1);
            unsigned int pb = __float_as_uint(pv);
            unsigned int lo = ishard ? (0xFFFFFFFFu - (unsigned int)p) : (unsigned int)p;
            key = ((unsigned long long)pb << 32) | (unsigned long long)lo;
        }
    }
    __syncthreads();
    if (t < NLIST_ && lcnt[t] > 0) lbeg[t] = atomicAdd(&cursor[t], lcnt[t]);
    __syncthreads();
    if (L >= 0) cand[(size_t)L*CAPL_ + lbeg[L] + lp] = key;
}

// ---------------- 2. exact ordered top-k per list ----------------
__global__ void __launch_bounds__(256, 2)
k_select2(const int* __restrict__ cursor, const unsigned long long* __restrict__ cand,
          int* __restrict__ sel_b, int* __restrict__ sel_p, int* __restrict__ sel_l) {
    __shared__ unsigned long long keys[CAP_];
    __shared__ unsigned long long wpart[2][4];
    int bid = blockIdx.x;
    int slot = bid >> 1, ishard = bid & 1;
    int h_take, e_take, base_off;
    plan_slot(cursor, slot, &h_take, &e_take, &base_off);
    int take = ishard ? h_take : e_take;
    if (take == 0) return;
    int off = base_off + (ishard ? 0 : h_take);
    int m = cursor[2*slot + ishard];
    const unsigned long long* g = cand + (size_t)(2*slot + ishard)*CAPL_;
    int t = threadIdx.x, lane = t & 63, w = t >> 6;
    bool fits = (m <= CAP_);
    if (fits) {
        for (int j = t; j < m; j += 256) keys[j] = g[j];
        __syncthreads();
    }
    int b = slot / NCLS_, c = slot - b*NCLS_;
    unsigned long long prev = ishard ? 0xFFFFFFFFFFFFFFFFull : 0ull;
    for (int it = 0; it < take; ++it) {
        unsigned long long best = ishard ? 0ull : 0xFFFFFFFFFFFFFFFFull;
        if (ishard) {
            for (int j = t; j < m; j += 256) {
                unsigned long long k = fits ? keys[j] : g[j];
                if (k < prev && k > best) best = k;
            }
        } else {
            for (int j = t; j < m; j += 256) {
                unsigned long long k = fits ? keys[j] : g[j];
                if (k > prev && k < best) best = k;
            }
        }
        #pragma unroll
        for (int d = 1; d < 64; d <<= 1) {
            unsigned long long o = __shfl_xor(best, d);
            if (ishard ? (o > best) : (o < best)) best = o;
        }
        if (lane == 0) wpart[it & 1][w] = best;
        __syncthreads();
        unsigned long long b0 = wpart[it & 1][0], b1 = wpart[it & 1][1];
        unsigned long long b2 = wpart[it & 1][2], b3 = wpart[it & 1][3];
        if (ishard) {
            unsigned long long hi01 = b0 > b1 ? b0 : b1;
            unsigned long long hi23 = b2 > b3 ? b2 : b3;
            prev = hi01 > hi23 ? hi01 : hi23;
        } else {
            unsigned long long lo01 = b0 < b1 ? b0 : b1;
            unsigned long long lo23 = b2 < b3 ? b2 : b3;
            prev = lo01 < lo23 ? lo01 : lo23;
        }
        if (t == 0) {
            unsigned int lo = (unsigned int)(prev & 0xFFFFFFFFull);
            int p = ishard ? (int)(0xFFFFFFFFu - lo) : (int)lo;
            sel_b[off+it] = b; sel_p[off+it] = p; sel_l[off+it] = c;
        }
    }
}

// ---------------- 3. gather + l2-normalize -> bf16 (1 wave / vector) ----------------
__global__ void __launch_bounds__(64)
k_gather(const float* __restrict__ pf, const float* __restrict__ pm,
         const int* __restrict__ cursor, const int* __restrict__ sel_b,
         const int* __restrict__ sel_p,
         unsigned short* __restrict__ sfh, unsigned short* __restrict__ km) {
    int bid = blockIdx.x;
    int s = bid >> 2, vec = bid & 3;
    int n = plan_total_n(cursor, nullptr);
    if (s >= n) return;
    int b = sel_b[s], p = sel_p[s];
    int lane = threadIdx.x;
    const float* src;
    unsigned short* dst;
    if (vec == 0)      { src = pf + (size_t)(b*C_)*N_ + p;          dst = sfh + (size_t)s*C_; }
    else if (vec == 1) { src = pm + (size_t)((2*B_+b)*C_)*N_ + p;   dst = km + (size_t)s*C_; }
    else if (vec == 2) { src = pm + (size_t)((0*B_+b)*C_)*N_ + p;   dst = km + (size_t)(n + 2*s)*C_; }
    else               { src = pm + (size_t)((1*B_+b)*C_)*N_ + p;   dst = km + (size_t)(n + 2*s + 1)*C_; }
    float x[4]; float ss = 0.f;
    #pragma unroll
    for (int q = 0; q < 4; ++q) { x[q] = src[(size_t)(lane + 64*q)*N_]; ss += x[q]*x[q]; }
    #pragma unroll
    for (int d = 1; d < 64; d <<= 1) ss += __shfl_xor(ss, d);
    float inv = 1.f / fmaxf(sqrtf(ss), 1e-12f);
    #pragma unroll
    for (int q = 0; q < 4; ++q) dst[lane + 64*q] = f2bf(x[q] * inv);
}

// ---------------- 4. full-row MFMA + fixed-shift softmax loss (+ last-block final) ----------------
// Blocks 0..63: feat rows (16/block, A=B=sfh, M=n).  Blocks 64..127: mask rows (A=B=km, M=3n).
// Fixed softmax shift m=10 (logits bounded by ~10): per value one exp, no max tracking.
// Each block writes FINAL paf/pam rows; last block reduces to out.
__global__ void __launch_bounds__(256, 2)
k_rows_full(const int* __restrict__ cursor, const unsigned short* __restrict__ sfh,
            const unsigned short* __restrict__ km, const int* __restrict__ sel_l,
            float* __restrict__ paf, float* __restrict__ pam,
            int* __restrict__ counter, float* __restrict__ out) {
    int total;
    const int n = plan_total_n(cursor, &total);
    const int t = threadIdx.x;
    const bool maskmode = (blockIdx.x >= 64);
    const int r0 = (maskmode ? (int)blockIdx.x - 64 : (int)blockIdx.x) * 16;
    __shared__ int sl[MAXN_];
    __shared__ float red[16][3];
    const bool active = (n > 0) && (r0 < n);
    if (active) {
        for (int j = t; j < n; j += 256) sl[j] = sel_l[j];
        if (t < 16) { red[t][0] = 0.f; red[t][1] = 0.f; red[t][2] = 0.f; }
        __syncthreads();
        const unsigned short* buf = maskmode ? km : sfh;
        const int M = maskmode ? 3*n : n;
        const int w = t >> 6, lane = t & 63;
        const int lrow = lane & 15, koff = (lane >> 4) * 8;
        const bf16x8 zero8 = {0,0,0,0,0,0,0,0};
        // A fragment: rows r0..r0+15, full K in registers
        bf16x8 af[8];
        const int arow = r0 + lrow;
        const bool aok = (arow < n);
        #pragma unroll
        for (int ch = 0; ch < 8; ++ch)
            af[ch] = aok ? *(const bf16x8*)&buf[(size_t)arow*C_ + ch*32 + koff] : zero8;
        // my 4 output rows (C layout: row = (lane>>4)*4+q)
        int rowq[4], laq[4]; bool rokq[4];
        #pragma unroll
        for (int q = 0; q < 4; ++q) {
            rowq[q] = r0 + ((lane >> 4) << 2) + q;
            rokq[q] = rowq[q] < n;
            laq[q] = rokq[q] ? sl[rowq[q]] : -1;
        }
        float dn[4] = {0,0,0,0}, S[4] = {0,0,0,0}, cnt[4] = {0,0,0,0};
        const int ncg = (M + 15) >> 4;
        for (int cg = w; cg < ncg; cg += 4) {
            const int bcol = cg*16 + lrow;
            const bool bok = (bcol < M);
            const unsigned short* bsrc = buf + (size_t)bcol*C_ + koff;
            f32x4 acc = (f32x4){0.f,0.f,0.f,0.f};
            #pragma unroll
            for (int ch = 0; ch < 8; ++ch) {
                bf16x8 bfr = bok ? *(const bf16x8*)&bsrc[ch*32] : zero8;
                acc = __builtin_amdgcn_mfma_f32_16x16x32_bf16(af[ch], bfr, acc, 0, 0, 0);
            }
            // epilogue: this lane's col = cg*16 + (lane&15)
            const int col = cg*16 + lrow;
            const bool colok = (col < M);
            int lcl = -1;
            if (colok) {
                int qm = col;
                if (maskmode) { int qq = col - n; qm = (col < n) ? col : (qq < n ? qq : qq - n); }
                lcl = sl[qm];
            }
            #pragma unroll
            for (int q = 0; q < 4; ++q) {
                if (!colok || !rokq[q]) continue;
                float Lv = acc[q] * 10.0f;
                if (!maskmode) {
                    if (col != rowq[q]) {
                        dn[q] += expf(Lv - 10.0f);
                        if (lcl == laq[q]) { S[q] += Lv; cnt[q] += 1.f; }
                    }
                } else {
                    bool tot = (lcl == laq[q]) && (col >= n || col != rowq[q]);
                    if (tot) { S[q] += Lv; cnt[q] += 1.f; }
                    else dn[q] += expf(Lv - 10.0f);
                }
            }
        }
        // reduce across the 16 lanes sharing the same rows
        #pragma unroll
        for (int d = 1; d < 16; d <<= 1) {
            #pragma unroll
            for (int q = 0; q < 4; ++q) {
                dn[q]  += __shfl_xor(dn[q], d, 16);
                S[q]   += __shfl_xor(S[q], d, 16);
                cnt[q] += __shfl_xor(cnt[q], d, 16);
            }
        }
        if (lrow == 0) {
            #pragma unroll
            for (int q = 0; q < 4; ++q) {
                int rl = ((lane >> 4) << 2) + q;
                atomicAdd(&red[rl][0], dn[q]);
                atomicAdd(&red[rl][1], S[q]);
                atomicAdd(&red[rl][2], cnt[q]);
            }
        }
        __syncthreads();
        if (t < 16 && (r0 + t) < n) {
            float d = red[t][0], s = red[t][1], c = red[t][2];
            float lg = logf(d + 1e-16f);
            float val = (s - c*10.0f - c*lg) / (c + 1e-16f);
            (maskmode ? pam : paf)[r0 + t] = val;
        }
    }
    // last-block final reduce
    __threadfence();
    __shared__ int amLast;
    if (t == 0) amLast = (atomicAdd(counter, 1) == 127);
    __syncthreads();
    if (!amLast) return;
    __threadfence();
    __shared__ float redf[4][2];
    int lane = t & 63, w = t >> 6;
    float sf = 0.f, sm = 0.f;
    for (int a = t; a < n; a += 256) { sf += paf[a]; sm += pam[a]; }
    #pragma unroll
    for (int d = 1; d < 64; d <<= 1) { sf += __shfl_xor(sf, d); sm += __shfl_xor(sm, d); }
    if (lane == 0) { redf[w][0] = sf; redf[w][1] = sm; }
    __syncthreads();
    if (t == 0) {
        sf = redf[0][0] + redf[1][0] + redf[2][0] + redf[3][0];
        sm = redf[0][1] + redf[1][1] + redf[2][1] + redf[3][1];
        if (total == 0 || n == 0) { out[0] = 0.f; out[1] = 0.f; }
        else {
            float scale = (float)(-(0.1/0.07));
            out[0] = scale * (sf / (float)n) * 0.1f;   // FEAT_W
            out[1] = scale * (sm / (float)n) * 0.1f;   // MASK_W
        }
    }
}

extern "C" void kernel_launch(void* const* d_in, const int* in_sizes, int n_in,
                              void* d_out, int out_size, void* d_ws, size_t ws_size,
                              hipStream_t stream) {
    const float* pf  = (const float*)d_in[0];   // proj_feats (B,C,H,W)
    const float* seg = (const float*)d_in[1];   // seg_logits (B,19,H,W)
    const int*   gt  = (const int*)d_in[2];     // groundtruth (B,1,H,W)
    const float* pm  = (const float*)d_in[3];   // proj_masks (3,B,256,H,W)
    float* out = (float*)d_out;
    char* ws = (char*)d_ws;

    int*   cursor   = (int*)(ws + OFF_CURS);
    int*   counter  = cursor + NLIST_;
    int*   sel_b    = (int*)(ws + OFF_SELB);
    int*   sel_p    = (int*)(ws + OFF_SELP);
    int*   sel_l    = (int*)(ws + OFF_SELL);
    unsigned short* sfh = (unsigned short*)(ws + OFF_SFH);
    unsigned short* km  = (unsigned short*)(ws + OFF_KMH);
    float* paf      = (float*)(ws + OFF_PAF);
    float* pam      = (float*)(ws + OFF_PAM);
    unsigned long long* cand = (unsigned long long*)(ws + OFF_CAND);

    hipMemsetAsync(ws + OFF_CURS, 0, 512, stream);   // cursors + finish counter

    k_softmax_scatter<<<NBLK_, 256, 0, stream>>>(seg, gt, cursor, cand);
    k_select2<<<NLIST_, 256, 0, stream>>>(cursor, cand, sel_b, sel_p, sel_l);
    k_gather<<<4*MAXN_, 64, 0, stream>>>(pf, pm, cursor, sel_b, sel_p, sfh, km);
    k_rows_full<<<128, 256, 0, stream>>>(cursor, sfh, km, sel_l, paf, pam, counter, out);
}

// Round 9
// 109.741 us; speedup vs baseline: 1.6678x; 1.6678x over previous
//
#include <hip/hip_runtime.h>
#include <hip/hip_bf16.h>
#include <math.h>

#define B_ 2
#define NCLS_ 19
#define N_ 25600
#define C_ 256
#define MAXN_ 1024
#define THRESH_ 100
#define MAXSAMP_ 1024
#define NLIST_ (B_*NCLS_*2)
#define NHIST_ (B_*NCLS_)
#define NBLK_ 200              // (B_*N_+255)/256
#define CAP_ 6144
#define CAPL_ 25600            // fixed capacity per candidate list
#define NRF_ 32                // feat key ranges (MAXN/32)
#define NRM_ 96                // mask key ranges (3*MAXN/32)

typedef __attribute__((ext_vector_type(8))) short bf16x8;
typedef __attribute__((ext_vector_type(4))) float f32x4;

// ---------------- workspace layout (bytes) ----------------
constexpr size_t OFF_CURS = 0;                                   // NLIST ints + finish counter (512 B, memset each call)
constexpr size_t OFF_SELB = 512;
constexpr size_t OFF_SELP = OFF_SELB + (size_t)MAXN_*4;
constexpr size_t OFF_SELL = OFF_SELP + (size_t)MAXN_*4;
constexpr size_t OFF_SFH  = OFF_SELL + (size_t)MAXN_*4;          // MAXN*C bf16
constexpr size_t OFF_KMH  = OFF_SFH + (size_t)MAXN_*C_*2;        // 3*MAXN*C bf16
constexpr size_t OFF_PAF  = OFF_KMH + (size_t)3*MAXN_*C_*2;
constexpr size_t OFF_PAM  = OFF_PAF + (size_t)MAXN_*4;
constexpr size_t OFF_PFP  = OFF_PAM + (size_t)MAXN_*4;           // MAXN*NRF float4
constexpr size_t OFF_PMP  = OFF_PFP + (size_t)MAXN_*NRF_*16;     // MAXN*NRM float4
constexpr size_t OFF_CAND = OFF_PMP + (size_t)MAXN_*NRM_*16;     // NLIST*CAPL u64 (~15.6 MB)

__device__ __forceinline__ unsigned short f2bf(float x) {
    unsigned u = __float_as_uint(x);
    unsigned r = (u + 0x7FFFu + ((u >> 16) & 1u)) >> 16;   // RNE
    return (unsigned short)r;
}

// ---- mining plan recomputed from cursor counts (cheap: 76 L2-hot ints) ----
__device__ __forceinline__ void plan_takes(int ne, int nh, int n_view, int* h, int* e) {
    int nhk, nek;
    bool hb = 2*nh >= n_view, eb = 2*ne >= n_view;
    if (hb && eb)      { nhk = n_view/2; nek = n_view - nhk; }
    else if (hb)       { nek = ne;       nhk = n_view - nek; }
    else if (eb)       { nhk = nh;       nek = n_view - nhk; }
    else               { nhk = nh;       nek = ne; }
    *h = nhk < nh ? nhk : nh;
    *e = nek < ne ? nek : ne;
}

__device__ __forceinline__ int plan_total_n(const int* __restrict__ cursor, int* o_total) {
    int total = 0;
    for (int i = 0; i < NHIST_; ++i)
        if (cursor[2*i] + cursor[2*i+1] > THRESH_) total++;
    int n_view = 0;
    if (total > 0) { n_view = MAXSAMP_ / total; if (n_view > THRESH_) n_view = THRESH_; }
    int off = 0;
    for (int i = 0; i < NHIST_; ++i) {
        int ne = cursor[2*i], nh = cursor[2*i+1];
        if (ne + nh > THRESH_) { int h, e; plan_takes(ne, nh, n_view, &h, &e); off += h + e; }
    }
    if (o_total) *o_total = total;
    return off;
}

__device__ __forceinline__ void plan_slot(const int* __restrict__ cursor, int slot,
                                          int* h_take, int* e_take, int* off_out) {
    int total = 0;
    for (int i = 0; i < NHIST_; ++i)
        if (cursor[2*i] + cursor[2*i+1] > THRESH_) total++;
    int n_view = 0;
    if (total > 0) { n_view = MAXSAMP_ / total; if (n_view > THRESH_) n_view = THRESH_; }
    int off = 0, ht = 0, et = 0, myoff = 0;
    for (int i = 0; i < NHIST_; ++i) {
        int ne = cursor[2*i], nh = cursor[2*i+1];
        int h = 0, e = 0;
        if (ne + nh > THRESH_) plan_takes(ne, nh, n_view, &h, &e);
        if (i == slot) { ht = h; et = e; myoff = off; }
        off += h + e;
    }
    *h_take = ht; *e_take = et; *off_out = myoff;
}

// ---------------- 1. fused softmax/argmax + candidate scatter ----------------
__global__ void __launch_bounds__(256, 2)
k_softmax_scatter(const float* __restrict__ seg, const int* __restrict__ gt,
                  int* __restrict__ cursor, unsigned long long* __restrict__ cand) {
    __shared__ int lcnt[NLIST_];
    __shared__ int lbeg[NLIST_];
    int t = threadIdx.x;
    if (t < NLIST_) lcnt[t] = 0;
    __syncthreads();
    int idx = blockIdx.x * 256 + t;
    int L = -1, lp = 0;
    unsigned long long key = 0;
    if (idx < B_*N_) {
        int b = idx / N_, p = idx - b*N_;
        int lab = gt[idx];
        if (lab >= 0 && lab < NCLS_) {
            const float* base = seg + (size_t)b*NCLS_*N_ + p;
            float v[NCLS_];
            float mx = -INFINITY; int am = 0;
            #pragma unroll
            for (int k = 0; k < NCLS_; ++k) {
                float x = base[(size_t)k*N_];
                v[k] = x;
                if (x > mx) { mx = x; am = k; }
            }
            float ssum = 0.f, pv = 0.f;
            #pragma unroll
            for (int k = 0; k < NCLS_; ++k) {
                float e = expf(v[k] - mx);
                ssum += e;
                pv = (lab == k) ? e : pv;
            }
            pv /= ssum;
            int ishard = (am != lab) ? 1 : 0;
            L = (b*NCLS_ + lab)*2 + ishard;
            lp = atomicAdd(&lcnt[L], 1);
            unsigned int pb = __float_as_uint(pv);
            unsigned int lo = ishard ? (0xFFFFFFFFu - (unsigned int)p) : (unsigned int)p;
            key = ((unsigned long long)pb << 32) | (unsigned long long)lo;
        }
    }
    __syncthreads();
    if (t < NLIST_ && lcnt[t] > 0) lbeg[t] = atomicAdd(&cursor[t], lcnt[t]);
    __syncthreads();
    if (L >= 0) cand[(size_t)L*CAPL_ + lbeg[L] + lp] = key;
}

// ---------------- 2. exact ordered top-k per list ----------------
__global__ void __launch_bounds__(256, 2)
k_select2(const int* __restrict__ cursor, const unsigned long long* __restrict__ cand,
          int* __restrict__ sel_b, int* __restrict__ sel_p, int* __restrict__ sel_l) {
    __shared__ unsigned long long keys[CAP_];
    __shared__ unsigned long long wpart[2][4];
    int bid = blockIdx.x;
    int slot = bid >> 1, ishard = bid & 1;
    int h_take, e_take, base_off;
    plan_slot(cursor, slot, &h_take, &e_take, &base_off);
    int take = ishard ? h_take : e_take;
    if (take == 0) return;
    int off = base_off + (ishard ? 0 : h_take);
    int m = cursor[2*slot + ishard];
    const unsigned long long* g = cand + (size_t)(2*slot + ishard)*CAPL_;
    int t = threadIdx.x, lane = t & 63, w = t >> 6;
    bool fits = (m <= CAP_);
    if (fits) {
        for (int j = t; j < m; j += 256) keys[j] = g[j];
        __syncthreads();
    }
    int b = slot / NCLS_, c = slot - b*NCLS_;
    unsigned long long prev = ishard ? 0xFFFFFFFFFFFFFFFFull : 0ull;
    for (int it = 0; it < take; ++it) {
        unsigned long long best = ishard ? 0ull : 0xFFFFFFFFFFFFFFFFull;
        if (ishard) {
            for (int j = t; j < m; j += 256) {
                unsigned long long k = fits ? keys[j] : g[j];
                if (k < prev && k > best) best = k;
            }
        } else {
            for (int j = t; j < m; j += 256) {
                unsigned long long k = fits ? keys[j] : g[j];
                if (k > prev && k < best) best = k;
            }
        }
        #pragma unroll
        for (int d = 1; d < 64; d <<= 1) {
            unsigned long long o = __shfl_xor(best, d);
            if (ishard ? (o > best) : (o < best)) best = o;
        }
        if (lane == 0) wpart[it & 1][w] = best;
        __syncthreads();
        unsigned long long b0 = wpart[it & 1][0], b1 = wpart[it & 1][1];
        unsigned long long b2 = wpart[it & 1][2], b3 = wpart[it & 1][3];
        if (ishard) {
            unsigned long long hi01 = b0 > b1 ? b0 : b1;
            unsigned long long hi23 = b2 > b3 ? b2 : b3;
            prev = hi01 > hi23 ? hi01 : hi23;
        } else {
            unsigned long long lo01 = b0 < b1 ? b0 : b1;
            unsigned long long lo23 = b2 < b3 ? b2 : b3;
            prev = lo01 < lo23 ? lo01 : lo23;
        }
        if (t == 0) {
            unsigned int lo = (unsigned int)(prev & 0xFFFFFFFFull);
            int p = ishard ? (int)(0xFFFFFFFFu - lo) : (int)lo;
            sel_b[off+it] = b; sel_p[off+it] = p; sel_l[off+it] = c;
        }
    }
}

// ---------------- 3. gather + l2-normalize -> bf16 (1 wave / vector) ----------------
__global__ void __launch_bounds__(64)
k_gather(const float* __restrict__ pf, const float* __restrict__ pm,
         const int* __restrict__ cursor, const int* __restrict__ sel_b,
         const int* __restrict__ sel_p,
         unsigned short* __restrict__ sfh, unsigned short* __restrict__ km) {
    int bid = blockIdx.x;
    int s = bid >> 2, vec = bid & 3;
    int n = plan_total_n(cursor, nullptr);
    if (s >= n) return;
    int b = sel_b[s], p = sel_p[s];
    int lane = threadIdx.x;
    const float* src;
    unsigned short* dst;
    if (vec == 0)      { src = pf + (size_t)(b*C_)*N_ + p;          dst = sfh + (size_t)s*C_; }
    else if (vec == 1) { src = pm + (size_t)((2*B_+b)*C_)*N_ + p;   dst = km + (size_t)s*C_; }
    else if (vec == 2) { src = pm + (size_t)((0*B_+b)*C_)*N_ + p;   dst = km + (size_t)(n + 2*s)*C_; }
    else               { src = pm + (size_t)((1*B_+b)*C_)*N_ + p;   dst = km + (size_t)(n + 2*s + 1)*C_; }
    float x[4]; float ss = 0.f;
    #pragma unroll
    for (int q = 0; q < 4; ++q) { x[q] = src[(size_t)(lane + 64*q)*N_]; ss += x[q]*x[q]; }
    #pragma unroll
    for (int d = 1; d < 64; d <<= 1) ss += __shfl_xor(ss, d);
    float inv = 1.f / fmaxf(sqrtf(ss), 1e-12f);
    #pragma unroll
    for (int q = 0; q < 4; ++q) dst[lane + 64*q] = f2bf(x[q] * inv);
}

// ---------------- 4. fused MFMA GEMM + masked-softmax partials ----------------
// blockIdx.y < 16 : feat  (A=B=sfh, M=n,  part=pfp, NR=32)
// blockIdx.y >= 16: mask  (A=B=km,  M=3n, part=pmp, NR=96)
__global__ void __launch_bounds__(256, 4)
k_rows_mfma(const int* __restrict__ cursor, const unsigned short* __restrict__ sfh,
            const unsigned short* __restrict__ km, const int* __restrict__ sel_l,
            float4* __restrict__ pfp, float4* __restrict__ pmp) {
    const int n = plan_total_n(cursor, nullptr);
    const bool maskmode = (blockIdx.y >= 16);
    const int yb = maskmode ? (blockIdx.y - 16) : blockIdx.y;
    const int M = maskmode ? 3*n : n;
    const int rbase = blockIdx.x * 64;
    const int cbase = yb * 64;
    if (rbase >= n || cbase >= M) return;
    const unsigned short* buf = maskmode ? km : sfh;
    float4* part = maskmode ? pmp : pfp;
    const int NR = maskmode ? NRM_ : NRF_;

    __shared__ int sl[MAXN_];
    const int t = threadIdx.x;
    for (int j = t; j < n; j += 256) sl[j] = sel_l[j];
    __syncthreads();

    const int wid = t >> 6, lane = t & 63;
    const int wr = wid >> 1, wc = wid & 1;
    const int r0 = rbase + wr*32;
    const int c0 = cbase + wc*32;
    const int lrow = lane & 15, lk = (lane >> 4) * 8;

    const bf16x8 zero8 = {0,0,0,0,0,0,0,0};
    f32x4 acc[2][2];
    #pragma unroll
    for (int i = 0; i < 2; ++i)
        #pragma unroll
        for (int j = 0; j < 2; ++j) acc[i][j] = (f32x4){0.f,0.f,0.f,0.f};

    for (int kk = 0; kk < C_; kk += 32) {
        bf16x8 af[2], bfr[2];
        #pragma unroll
        for (int i = 0; i < 2; ++i) {
            int r = r0 + i*16 + lrow;
            af[i] = (r < n) ? *(const bf16x8*)&buf[(size_t)r*C_ + kk + lk] : zero8;
        }
        #pragma unroll
        for (int j = 0; j < 2; ++j) {
            int c = c0 + j*16 + lrow;
            bfr[j] = (c < M) ? *(const bf16x8*)&buf[(size_t)c*C_ + kk + lk] : zero8;
        }
        #pragma unroll
        for (int i = 0; i < 2; ++i)
            #pragma unroll
            for (int j = 0; j < 2; ++j)
                acc[i][j] = __builtin_amdgcn_mfma_f32_16x16x32_bf16(af[i], bfr[j], acc[i][j], 0, 0, 0);
    }

    // epilogue: C layout: col = lane&15 (+j*16), row = (lane>>4)*4 + reg (+i*16)
    const int ri = yb*2 + wc;
    const int g4 = (lane >> 4) * 4;
    const int lc = lane & 15;
    #pragma unroll
    for (int i = 0; i < 2; ++i) {
        #pragma unroll
        for (int q = 0; q < 4; ++q) {
            int row = r0 + i*16 + g4 + q;
            bool rok = (row < n);
            int la = rok ? sl[row] : 0;
            float v0 = acc[i][0][q] * 10.0f;
            float v1 = acc[i][1][q] * 10.0f;
            int col0 = c0 + lc, col1 = c0 + 16 + lc;
            float m = -INFINITY;
            if (col0 < M) m = v0;
            if (col1 < M) m = fmaxf(m, v1);
            #pragma unroll
            for (int d = 1; d < 16; d <<= 1) m = fmaxf(m, __shfl_xor(m, d, 16));
            float dn = 0.f, S = 0.f, cnt = 0.f;
            #pragma unroll
            for (int jj = 0; jj < 2; ++jj) {
                int col = jj ? col1 : col0;
                float L = jj ? v1 : v0;
                if (col >= M) continue;
                if (!maskmode) {
                    if (col != row) {
                        dn += expf(L - m);
                        if (sl[col] == la) { S += L; cnt += 1.f; }
                    }
                } else {
                    int qq = col - n;
                    int qm = (col < n) ? col : (qq < n ? qq : qq - n);
                    bool tot = (sl[qm] == la) && (col >= n || col != row);
                    if (tot) { S += L; cnt += 1.f; }
                    else dn += expf(L - m);
                }
            }
            #pragma unroll
            for (int d = 1; d < 16; d <<= 1) {
                dn  += __shfl_xor(dn, d, 16);
                S   += __shfl_xor(S, d, 16);
                cnt += __shfl_xor(cnt, d, 16);
            }
            if (rok && lc == 0) part[(size_t)row*NR + ri] = make_float4(m, dn, S, cnt);
        }
    }
}

// ---------------- 5. combine partials (1 wave / row) + last-block final ----------------
__global__ void __launch_bounds__(256, 2)
k_combine_final(const int* __restrict__ cursor, const float4* __restrict__ pfp,
                const float4* __restrict__ pmp, float* __restrict__ paf,
                float* __restrict__ pam, int* __restrict__ counter,
                float* __restrict__ out) {
    int total;
    int n = plan_total_n(cursor, &total);
    int t = threadIdx.x, lane = t & 63, w = t >> 6;
    int r = blockIdx.x*4 + w;
    if (r < n) {
        // ---- feat: lane i holds partial i (nrF <= 32) ----
        int nrF = (n + 31) >> 5;
        float px = -INFINITY, py = 0.f, pz = 0.f, pw = 0.f;
        if (lane < nrF) {
            float4 p = pfp[(size_t)r*NRF_ + lane];
            px = p.x; py = p.y; pz = p.z; pw = p.w;
        }
        float mg = px;
        #pragma unroll
        for (int d = 1; d < 64; d <<= 1) mg = fmaxf(mg, __shfl_xor(mg, d));
        float dn = (lane < nrF) ? py * expf(px - mg) : 0.f;
        float S = pz, cnt = pw;
        #pragma unroll
        for (int d = 1; d < 64; d <<= 1) {
            dn += __shfl_xor(dn, d); S += __shfl_xor(S, d); cnt += __shfl_xor(cnt, d);
        }
        if (lane == 0) {
            float lg = logf(dn + 1e-16f);
            paf[r] = (S - cnt*mg - cnt*lg) / (cnt + 1e-16f);
        }
        // ---- mask: lane handles partials lane and lane+64 (nrM <= 96) ----
        int nrM = (3*n + 31) >> 5;
        float qx0 = -INFINITY, qy0 = 0.f, qz0 = 0.f, qw0 = 0.f;
        float qx1 = -INFINITY, qy1 = 0.f, qz1 = 0.f, qw1 = 0.f;
        if (lane < nrM) {
            float4 p = pmp[(size_t)r*NRM_ + lane];
            qx0 = p.x; qy0 = p.y; qz0 = p.z; qw0 = p.w;
        }
        if (64 + lane < nrM) {
            float4 p = pmp[(size_t)r*NRM_ + 64 + lane];
            qx1 = p.x; qy1 = p.y; qz1 = p.z; qw1 = p.w;
        }
        float mg2 = fmaxf(qx0, qx1);
        #pragma unroll
        for (int d = 1; d < 64; d <<= 1) mg2 = fmaxf(mg2, __shfl_xor(mg2, d));
        float dn2 = 0.f;
        if (lane < nrM)      dn2 += qy0 * expf(qx0 - mg2);
        if (64 + lane < nrM) dn2 += qy1 * expf(qx1 - mg2);
        float S2 = qz0 + qz1, cnt2 = qw0 + qw1;
        #pragma unroll
        for (int d = 1; d < 64; d <<= 1) {
            dn2 += __shfl_xor(dn2, d); S2 += __shfl_xor(S2, d); cnt2 += __shfl_xor(cnt2, d);
        }
        if (lane == 0) {
            float lg = logf(dn2 + 1e-16f);
            pam[r] = (S2 - cnt2*mg2 - cnt2*lg) / (cnt2 + 1e-16f);
        }
    }
    // ---- last-block final reduce ----
    __threadfence();
    __shared__ int amLast;
    if (t == 0) amLast = (atomicAdd(counter, 1) == (int)gridDim.x - 1);
    __syncthreads();
    if (!amLast) return;
    __threadfence();
    __shared__ float redf[4][2];
    float sf = 0.f, sm = 0.f;
    for (int a = t; a < n; a += 256) { sf += paf[a]; sm += pam[a]; }
    #pragma unroll
    for (int d = 1; d < 64; d <<= 1) { sf += __shfl_xor(sf, d); sm += __shfl_xor(sm, d); }
    if (lane == 0) { redf[w][0] = sf; redf[w][1] = sm; }
    __syncthreads();
    if (t == 0) {
        sf = redf[0][0] + redf[1][0] + redf[2][0] + redf[3][0];
        sm = redf[0][1] + redf[1][1] + redf[2][1] + redf[3][1];
        if (total == 0 || n == 0) { out[0] = 0.f; out[1] = 0.f; }
        else {
            float scale = (float)(-(0.1/0.07));
            out[0] = scale * (sf / (float)n) * 0.1f;   // FEAT_W
            out[1] = scale * (sm / (float)n) * 0.1f;   // MASK_W
        }
    }
}

extern "C" void kernel_launch(void* const* d_in, const int* in_sizes, int n_in,
                              void* d_out, int out_size, void* d_ws, size_t ws_size,
                              hipStream_t stream) {
    const float* pf  = (const float*)d_in[0];   // proj_feats (B,C,H,W)
    const float* seg = (const float*)d_in[1];   // seg_logits (B,19,H,W)
    const int*   gt  = (const int*)d_in[2];     // groundtruth (B,1,H,W)
    const float* pm  = (const float*)d_in[3];   // proj_masks (3,B,256,H,W)
    float* out = (float*)d_out;
    char* ws = (char*)d_ws;

    int*   cursor   = (int*)(ws + OFF_CURS);
    int*   counter  = cursor + NLIST_;
    int*   sel_b    = (int*)(ws + OFF_SELB);
    int*   sel_p    = (int*)(ws + OFF_SELP);
    int*   sel_l    = (int*)(ws + OFF_SELL);
    unsigned short* sfh = (unsigned short*)(ws + OFF_SFH);
    unsigned short* km  = (unsigned short*)(ws + OFF_KMH);
    float* paf      = (float*)(ws + OFF_PAF);
    float* pam      = (float*)(ws + OFF_PAM);
    float4* pfp     = (float4*)(ws + OFF_PFP);
    float4* pmp     = (float4*)(ws + OFF_PMP);
    unsigned long long* cand = (unsigned long long*)(ws + OFF_CAND);

    hipMemsetAsync(ws + OFF_CURS, 0, 512, stream);   // cursors + finish counter

    k_softmax_scatter<<<NBLK_, 256, 0, stream>>>(seg, gt, cursor, cand);
    k_select2<<<NLIST_, 256, 0, stream>>>(cursor, cand, sel_b, sel_p, sel_l);
    k_gather<<<4*MAXN_, 64, 0, stream>>>(pf, pm, cursor, sel_b, sel_p, sfh, km);
    k_rows_mfma<<<dim3(MAXN_/64, 64), 256, 0, stream>>>(cursor, sfh, km, sel_l, pfp, pmp);
    k_combine_final<<<256, 256, 0, stream>>>(cursor, pfp, pmp, paf, pam, counter, out);
}